// Round 6
// baseline (122.353 us; speedup 1.0000x reference)
//
#include <hip/hip_runtime.h>
#include <hip/hip_bf16.h>
#include <cstdint>
#include <cstddef>

#define B_  2
#define Q_  256
#define KL  2048
#define D_  256
#define H_  8
#define HD_ 32
#define CH_ 256

typedef _Float16 f16;
typedef __fp16 fp16x2 __attribute__((ext_vector_type(2)));
typedef _Float16 f16x8 __attribute__((ext_vector_type(8)));
typedef unsigned short ushortv4 __attribute__((ext_vector_type(4)));
typedef unsigned int uintv4 __attribute__((ext_vector_type(4)));
typedef float f32x4 __attribute__((ext_vector_type(4)));

union UH  { fp16x2 h; unsigned int u; };
union UH8 { f16x8 h; unsigned int u[4]; };

__device__ __forceinline__ unsigned int pkrtz(float a, float b) {
  UH r; r.h = __builtin_amdgcn_cvt_pkrtz(a, b); return r.u;
}
__device__ __forceinline__ unsigned short f16bits(float a) {
  return (unsigned short)(pkrtz(a, 0.f) & 0xffffu);
}
__device__ __forceinline__ unsigned int pk_fma(unsigned int a, unsigned int b,
                                               unsigned int c) {
  unsigned int d;
  asm("v_pk_fma_f16 %0, %1, %2, %3" : "=v"(d) : "v"(a), "v"(b), "v"(c));
  return d;
}
__device__ __forceinline__ unsigned int pk_max0(unsigned int a) {
  unsigned int d;
  asm("v_pk_max_f16 %0, %1, %2" : "=v"(d) : "v"(a), "v"(0u));
  return d;
}
__device__ __forceinline__ f16x8 pack8h(float4 a0, float4 a1) {
  UH8 u;
  u.u[0] = pkrtz(a0.x, a0.y);
  u.u[1] = pkrtz(a0.z, a0.w);
  u.u[2] = pkrtz(a1.x, a1.y);
  u.u[3] = pkrtz(a1.z, a1.w);
  return u.h;
}

// ---------- q projection: qp[row][n] (fp32 out)
__global__ __launch_bounds__(256) void gemm_q(const float* __restrict__ A,
                                              const float* __restrict__ W,
                                              const float* __restrict__ bias,
                                              float* __restrict__ out) {
  int nt = blockIdx.x & 3, mt = blockIdx.x >> 2;
  int t = threadIdx.x, w = t >> 6, l = t & 63;
  int m0 = mt * 16, n0 = nt * 64 + w * 16;
  int r = l & 15, g = l >> 4;
  const float* arow = A + (size_t)(m0 + r) * D_;
  const float* wrow = W + (size_t)(n0 + r) * D_;
  f32x4 acc = {0.f, 0.f, 0.f, 0.f};
#pragma unroll
  for (int s = 0; s < 8; ++s) {
    int kb = s * 32 + g * 8;
    f16x8 af = pack8h(*(const float4*)(arow + kb), *(const float4*)(arow + kb + 4));
    f16x8 bf = pack8h(*(const float4*)(wrow + kb), *(const float4*)(wrow + kb + 4));
    acc = __builtin_amdgcn_mfma_f32_16x16x32_f16(af, bf, acc, 0, 0, 0);
  }
  int n = n0 + r;
  float bb = bias[n];
#pragma unroll
  for (int rr = 0; rr < 4; ++rr)
    out[(size_t)(m0 + g * 4 + rr) * D_ + n] = acc[rr] + bb;
}

// ---------- kv projection: kp[b][k][c] f16; vt[b][h][dd][k] f16
__global__ __launch_bounds__(256) void gemm_kv(const float* __restrict__ img,
                                               const float* __restrict__ Wkv,
                                               const float* __restrict__ bkv,
                                               unsigned short* __restrict__ kp,
                                               unsigned short* __restrict__ vt) {
  int nt = blockIdx.x & 7, mt = (blockIdx.x >> 3) & 127, b = blockIdx.x >> 10;
  int t = threadIdx.x, w = t >> 6, l = t & 63;
  int m0 = mt * 16, n0 = nt * 64 + w * 16;
  int r = l & 15, g = l >> 4;
  const float* arow = img + (size_t)(b * KL + m0 + r) * D_;
  const float* wrow = Wkv + (size_t)(n0 + r) * D_;
  f32x4 acc = {0.f, 0.f, 0.f, 0.f};
#pragma unroll
  for (int s = 0; s < 8; ++s) {
    int kb = s * 32 + g * 8;
    f16x8 af = pack8h(*(const float4*)(arow + kb), *(const float4*)(arow + kb + 4));
    f16x8 bf = pack8h(*(const float4*)(wrow + kb), *(const float4*)(wrow + kb + 4));
    acc = __builtin_amdgcn_mfma_f32_16x16x32_f16(af, bf, acc, 0, 0, 0);
  }
  int n = n0 + r;
  float bb = bkv[n];
#pragma unroll
  for (int rr = 0; rr < 4; ++rr) acc[rr] += bb;
  if (n < 256) {
#pragma unroll
    for (int rr = 0; rr < 4; ++rr)
      kp[((size_t)b * KL + m0 + g * 4 + rr) * D_ + n] = f16bits(acc[rr]);
  } else {
    int c = n - 256, h = c >> 5, dd = c & 31;
    ushortv4 p;
#pragma unroll
    for (int rr = 0; rr < 4; ++rr) p[rr] = f16bits(acc[rr]);
    *(ushortv4*)(vt + ((size_t)(b * H_ + h) * HD_ + dd) * KL + m0 + g * 4) = p;
  }
}

// ---------- logits = QK^T*scale + CPB (f16 MFMA) + per-chunk softmax stats
__global__ __launch_bounds__(256, 4) void logits_cpb(
    const float* __restrict__ qp, const unsigned short* __restrict__ kp,
    const float* __restrict__ rd, const float* __restrict__ W1,
    const float* __restrict__ b1, const float* __restrict__ W2,
    const float* __restrict__ b2, unsigned short* __restrict__ lgb,
    float* __restrict__ stats) {
  int gid = blockIdx.x;
  int q = gid & 255, kc = (gid >> 8) & 7, b = gid >> 11;
  int t = threadIdx.x;
  __shared__ unsigned int w1xs[128], w1ys[128], b1ps[128];  // half2-packed
  __shared__ float qrow[D_];
  __shared__ unsigned short w2h[H_][264];
  __shared__ float b2s[H_];
  __shared__ float wmax[4][8];
  __shared__ float wsum[4][8];
  if (t < 128) {
    float4 wr = *(const float4*)(W1 + 4 * t);  // rows 2t, 2t+1 of W1[256][2]
    w1xs[t] = pkrtz(wr.x, wr.z);
    w1ys[t] = pkrtz(wr.y, wr.w);
    float2 bb = *(const float2*)(b1 + 2 * t);
    b1ps[t] = pkrtz(bb.x, bb.y);
  }
  qrow[t] = qp[(size_t)(b * Q_ + q) * D_ + t];
#pragma unroll
  for (int h = 0; h < H_; ++h) w2h[h][t] = f16bits(W2[h * CH_ + t]);
  if (t < H_) b2s[t] = b2[t];
  __syncthreads();

  int l = t & 63, w = t >> 6;
  int hp = l & 15, g = l >> 4, hq = hp & 7;
  int k0 = kc * 256 + w * 64;

  float x[4], y[4];
#pragma unroll
  for (int r = 0; r < 4; ++r) {
    float2 p = *(const float2*)(rd + ((size_t)(b * Q_ + q) * KL + k0 + r * 16 + hp) * 2);
    x[r] = p.x; y[r] = p.y;
  }
  unsigned int x2[4], y2[4];
#pragma unroll
  for (int r = 0; r < 4; ++r) { x2[r] = pkrtz(x[r], x[r]); y2[r] = pkrtz(y[r], y[r]); }

  const float scale = 0.17677669529663687f;  // 1/sqrt(32)
  unsigned int qf[4];
#pragma unroll
  for (int m = 0; m < 4; ++m)
    qf[m] = pkrtz(qrow[hq * 32 + g * 8 + 2 * m] * scale,
                  qrow[hq * 32 + g * 8 + 2 * m + 1] * scale);

  f32x4 acc[4];
#pragma unroll
  for (int r = 0; r < 4; ++r) acc[r] = (f32x4){0.f, 0.f, 0.f, 0.f};

  const unsigned short* kpb = kp + (size_t)b * KL * D_;
  const unsigned short* kprow[4];
#pragma unroll
  for (int r = 0; r < 4; ++r)
    kprow[r] = kpb + (size_t)(k0 + r * 16 + hp) * D_ + g * 8;

  f16x8 kf0[4], kf1[4];
#pragma unroll
  for (int r = 0; r < 4; ++r) kf0[r] = *(const f16x8*)(kprow[r]);

#pragma unroll
  for (int s = 0; s < 8; ++s) {
    if (s < 7) {
#pragma unroll
      for (int r = 0; r < 4; ++r) kf1[r] = *(const f16x8*)(kprow[r] + (s + 1) * 32);
    }
    int pidx = g * 4 + 16 * s;  // half2-pair index
    uintv4 wx = *(const uintv4*)&w1xs[pidx];
    uintv4 wy = *(const uintv4*)&w1ys[pidx];
    uintv4 bp = *(const uintv4*)&b1ps[pidx];
    f16x8 w2f = *(const f16x8*)&w2h[hq][g * 8 + 32 * s];
    UH8 bq;
#pragma unroll
    for (int m = 0; m < 4; ++m) bq.u[m] = (hp == s) ? qf[m] : 0u;
#pragma unroll
    for (int r = 0; r < 4; ++r) {
      UH8 az;
#pragma unroll
      for (int m = 0; m < 4; ++m)
        az.u[m] = pk_max0(pk_fma(x2[r], wx[m], pk_fma(y2[r], wy[m], bp[m])));
      acc[r] = __builtin_amdgcn_mfma_f32_16x16x32_f16(az.h, w2f, acc[r], 0, 0, 0);
      acc[r] = __builtin_amdgcn_mfma_f32_16x16x32_f16(kf0[r], bq.h, acc[r], 0, 0, 0);
    }
#pragma unroll
    for (int r = 0; r < 4; ++r) kf0[r] = kf1[r];
  }

  // epilogue: +b2, chunk stats, packed f16 stores
  int hx = hp & 7;
  float bh = b2s[hx];
  float m = -3.0e38f;
#pragma unroll
  for (int r = 0; r < 4; ++r)
#pragma unroll
    for (int rr = 0; rr < 4; ++rr) {
      acc[r][rr] += bh;
      m = fmaxf(m, acc[r][rr]);
    }
  m = fmaxf(m, __shfl_xor(m, 16));
  m = fmaxf(m, __shfl_xor(m, 32));
  if (l < 8) wmax[w][l] = m;
  __syncthreads();
  float mc = fmaxf(fmaxf(wmax[0][hx], wmax[1][hx]), fmaxf(wmax[2][hx], wmax[3][hx]));
  float ssum = 0.f;
#pragma unroll
  for (int r = 0; r < 4; ++r)
#pragma unroll
    for (int rr = 0; rr < 4; ++rr) ssum += __expf(acc[r][rr] - mc);
  ssum += __shfl_xor(ssum, 16);
  ssum += __shfl_xor(ssum, 32);
  if (l < 8) wsum[w][l] = ssum;

  if (hp < 8) {
    unsigned short* ob = lgb + ((size_t)(b * H_ + hp) * Q_ + q) * KL + k0;
#pragma unroll
    for (int r = 0; r < 4; ++r) {
      uint2 pk;
      pk.x = pkrtz(acc[r][0], acc[r][1]);
      pk.y = pkrtz(acc[r][2], acc[r][3]);
      *(uint2*)(ob + r * 16 + g * 4) = pk;
    }
  }
  __syncthreads();
  if (t < 8) {
    float mm = fmaxf(fmaxf(wmax[0][t], wmax[1][t]), fmaxf(wmax[2][t], wmax[3][t]));
    float ss = wsum[0][t] + wsum[1][t] + wsum[2][t] + wsum[3][t];
    *(float2*)(stats + (((size_t)(b * H_ + t) * Q_ + q) * 8 + kc) * 2) =
        make_float2(mm, ss);
  }
}

// ---------- fused softmax + PV, dd-split: block = (bh, qt, dd-half of 16)
__global__ __launch_bounds__(512) void sm_pv(const unsigned short* __restrict__ lgb,
                                             const float* __restrict__ stats,
                                             const unsigned short* __restrict__ vt,
                                             unsigned short* __restrict__ ctxb) {
  int gid = blockIdx.x;
  int dh = gid & 1, qt = (gid >> 1) & 15, bh = gid >> 5;
  int t = threadIdx.x;
  __shared__ float Ms[16], Ss[16];
  __shared__ float pacc[8][16][17];

  if (t < 16) {
    const float* sp = stats + ((size_t)bh * Q_ + qt * 16 + t) * 16;
    float M = -3.0e38f;
#pragma unroll
    for (int kc = 0; kc < 8; ++kc) M = fmaxf(M, sp[2 * kc]);
    float S = 0.f;
#pragma unroll
    for (int kc = 0; kc < 8; ++kc) S += sp[2 * kc + 1] * __expf(sp[2 * kc] - M);
    Ms[t] = M;
    Ss[t] = 1.0f / S;
  }
  __syncthreads();

  int l = t & 63, w = t >> 6;
  int qq = l & 15, g = l >> 4;
  float mq = Ms[qq];
  const unsigned short* lr2 =
      lgb + ((size_t)bh * Q_ + qt * 16 + qq) * KL + w * 256 + g * 8;
  const unsigned short* vb =
      vt + ((size_t)bh * HD_ + dh * 16 + qq) * KL + w * 256 + g * 8;
  f32x4 a0 = {0.f, 0.f, 0.f, 0.f};
#pragma unroll
  for (int step = 0; step < 8; ++step) {
    f16x8 raw = *(const f16x8*)(lr2 + step * 32);
    UH8 pa;
#pragma unroll
    for (int mI = 0; mI < 4; ++mI) {
      float p0 = __expf((float)raw[2 * mI] - mq);
      float p1 = __expf((float)raw[2 * mI + 1] - mq);
      pa.u[mI] = pkrtz(p0, p1);
    }
    f16x8 v0 = *(const f16x8*)(vb + step * 32);
    a0 = __builtin_amdgcn_mfma_f32_16x16x32_f16(pa.h, v0, a0, 0, 0, 0);
  }
#pragma unroll
  for (int rr = 0; rr < 4; ++rr) pacc[w][g * 4 + rr][qq] = a0[rr];
  __syncthreads();

  if (t < 256) {
    int qo = t >> 4, dd = t & 15;
    float sum = 0.f;
#pragma unroll
    for (int wv = 0; wv < 8; ++wv) sum += pacc[wv][qo][dd];
    sum *= Ss[qo];
    int b = bh >> 3, h = bh & 7;
    ctxb[((size_t)b * Q_ + qt * 16 + qo) * D_ + h * HD_ + dh * 16 + dd] =
        f16bits(sum);
  }
}

// ---------- out projection: out = ctxb(f16) @ Wo^T + bo (fp32 out)
__global__ __launch_bounds__(256) void gemm_o(const unsigned short* __restrict__ A,
                                              const float* __restrict__ W,
                                              const float* __restrict__ bias,
                                              float* __restrict__ out) {
  int nt = blockIdx.x & 3, mt = blockIdx.x >> 2;
  int t = threadIdx.x, w = t >> 6, l = t & 63;
  int m0 = mt * 16, n0 = nt * 64 + w * 16;
  int r = l & 15, g = l >> 4;
  const unsigned short* arow = A + (size_t)(m0 + r) * D_;
  const float* wrow = W + (size_t)(n0 + r) * D_;
  f32x4 acc = {0.f, 0.f, 0.f, 0.f};
#pragma unroll
  for (int s = 0; s < 8; ++s) {
    int kb = s * 32 + g * 8;
    f16x8 af = *(const f16x8*)(arow + kb);
    f16x8 bf = pack8h(*(const float4*)(wrow + kb), *(const float4*)(wrow + kb + 4));
    acc = __builtin_amdgcn_mfma_f32_16x16x32_f16(af, bf, acc, 0, 0, 0);
  }
  int n = n0 + r;
  float bb = bias[n];
#pragma unroll
  for (int rr = 0; rr < 4; ++rr)
    out[(size_t)(m0 + g * 4 + rr) * D_ + n] = acc[rr] + bb;
}

extern "C" void kernel_launch(void* const* d_in, const int* in_sizes, int n_in,
                              void* d_out, int out_size, void* d_ws, size_t ws_size,
                              hipStream_t stream) {
  const float* ent  = (const float*)d_in[0];
  const float* img  = (const float*)d_in[1];
  const float* rd   = (const float*)d_in[2];
  const float* Wq   = (const float*)d_in[3];
  const float* bq   = (const float*)d_in[4];
  const float* Wkv  = (const float*)d_in[5];
  const float* bkv  = (const float*)d_in[6];
  const float* W1   = (const float*)d_in[7];
  const float* b1   = (const float*)d_in[8];
  const float* W2   = (const float*)d_in[9];
  const float* b2   = (const float*)d_in[10];
  const float* Wo   = (const float*)d_in[11];
  const float* bo   = (const float*)d_in[12];
  float* out = (float*)d_out;

  char* ws = (char*)d_ws;
  float*          qp    = (float*)(ws + 0);                  //   524,288 fp32 [b][q][c]
  unsigned short* kp    = (unsigned short*)(ws + 524288);    // 2,097,152 f16 [b][kk][c]
  unsigned short* vt    = (unsigned short*)(ws + 2621440);   // 2,097,152 f16 [b][h][dd][kk]
  unsigned short* lgb   = (unsigned short*)(ws + 4718592);   // 16,777,216 f16 [b][h][q][kk]
  float*          stats = (float*)(ws + 21495808);           //   262,144 float2 [b][h][q][kc]
  unsigned short* ctxb  = (unsigned short*)(ws + 21757952);  //   262,144 f16 [b][q][c]

  gemm_q<<<dim3(128), dim3(256), 0, stream>>>(ent, Wq, bq, qp);
  gemm_kv<<<dim3(2048), dim3(256), 0, stream>>>(img, Wkv, bkv, kp, vt);
  logits_cpb<<<dim3(B_ * Q_ * 8), dim3(256), 0, stream>>>(qp, kp, rd, W1, b1, W2, b2, lgb, stats);
  sm_pv<<<dim3(B_ * H_ * 16 * 2), dim3(512), 0, stream>>>(lgb, stats, vt, ctxb);
  gemm_o<<<dim3(128), dim3(256), 0, stream>>>(ctxb, Wo, bo, out);
}